// Round 11
// baseline (20605.200 us; speedup 1.0000x reference)
//
#include <hip/hip_runtime.h>
#include <math.h>

#define Bsz 512
#define Tsz 1024
#define Vsz 27
#define Hsz 512
#define BH (Bsz * Hsz)
#define TV (Tsz * Vsz)
#define NBLK 256
#define NT 512      // 8 waves; wave = M-tile (16 batch rows)
#define BT 128      // batch rows per group (4 groups x 64 j-blocks)
#define HPc 8       // h' cols per block
#define NG 24       // gate rows per block (8r + 8z + 8n)
#define XSTR 36     // xs row stride (floats)
#define CPOL_WT 0x11  // sc0|sc1 write-through for h stores (coherence point)

typedef float f32x4 __attribute__((ext_vector_type(4)));
typedef short s16x8 __attribute__((ext_vector_type(8)));
typedef unsigned int u32x4 __attribute__((ext_vector_type(4)));
#define MFMA __builtin_amdgcn_mfma_f32_16x16x32_bf16

__device__ __forceinline__ unsigned short btrunc(float x) {   // bf16 RTZ bits
    return (unsigned short)(__float_as_uint(x) >> 16);
}
__device__ __forceinline__ float bup(unsigned short b) {
    return __uint_as_float(((unsigned)b) << 16);
}
__device__ __forceinline__ unsigned short brne(float x) {     // bf16 RNE bits
    unsigned u = __float_as_uint(x);
    return (unsigned short)((u + 0x7FFFu + ((u >> 16) & 1u)) >> 16);
}
__device__ __forceinline__ __amdgpu_buffer_rsrc_t make_rsrc(void* p, unsigned bytes) {
    return __builtin_amdgcn_make_buffer_rsrc(p, (short)0, (int)bytes, 0x00020000);
}
// A-loads: CACHED (L1/L2). Cross-step staleness handled by the per-step
// acquire fence in group_barrier; write-through h stores keep L3 current
// and L2 clean, so the fence's invalidate is the only coherence cost.
__device__ __forceinline__ s16x8 bload128_c(__amdgpu_buffer_rsrc_t rsrc, int voff) {
    u32x4 d = __builtin_amdgcn_raw_buffer_load_b128(rsrc, voff, 0, 0);
    return __builtin_bit_cast(s16x8, d);
}

__global__ void init_ws_kernel(unsigned short* __restrict__ hpl, unsigned* __restrict__ cnt) {
    size_t i = (size_t)blockIdx.x * 256 + threadIdx.x;   // 768 x 256 x 16B = 3 MB
    ((uint4*)hpl)[i] = make_uint4(0u, 0u, 0u, 0u);
    if (blockIdx.x == 0) cnt[threadIdx.x] = 0u;
}

// Barrier with acquire fence (R8-proven correct): relaxed add + relaxed poll,
// then ONE __threadfence() -> invalidates this XCD's stale clean lines of the
// h buffer (last cached at step i-2) before the next step's cached A-reads.
__device__ __forceinline__ void group_barrier(unsigned* c, unsigned target) {
    __syncthreads();
    if (threadIdx.x == 0) {
        __hip_atomic_fetch_add(c, 1u, __ATOMIC_RELAXED, __HIP_MEMORY_SCOPE_AGENT);
        while (__hip_atomic_load(c, __ATOMIC_RELAXED, __HIP_MEMORY_SCOPE_AGENT) < target)
            __builtin_amdgcn_s_sleep(2);
        __threadfence();   // acquire: one L1/L2 invalidate per step
    }
    __syncthreads();
}

__global__ __launch_bounds__(NT, 2) void gru_persist(
    const float* __restrict__ x, const float* __restrict__ W_ih,
    const float* __restrict__ W_hh, const float* __restrict__ b_ih,
    const float* __restrict__ b_hh, const float* __restrict__ W_dec,
    const float* __restrict__ b_dec, unsigned short* __restrict__ hpl,
    unsigned* __restrict__ cnt, float* __restrict__ out)
{
    // Fragment-linear streams: every ds_read_b128 is lane-contiguous 1KB.
    __shared__ unsigned short Bst[17 * 6 * 512];   // [c][tile][plane][ln][8] 102KB
    __shared__ unsigned short Dst[16 * 512];       // decode stream (j<2)     16KB
    __shared__ float xs[BT][XSTR];
    __shared__ float bihL[NG], bhhL[NG];

    const int tid = threadIdx.x;
    const int bt  = blockIdx.x & 3;     // batch group 0..3
    const int j   = blockIdx.x >> 2;    // h' tile 0..63
    const int b0  = bt * BT;
    const int g0  = j * HPc;

    // ---- one-time: build B-stream (triple-split W, fragment order) ----
    for (int idx = tid; idx < 17 * 6 * 512; idx += NT) {
        int e   = idx & 7;
        int ln2 = (idx >> 3) & 63;
        int rem = idx >> 9;            // (c*2+t)*3+p
        int p   = rem % 3;
        int ct  = rem / 3;
        int t   = ct & 1;
        int c   = ct >> 1;
        int cc2 = ln2 & 15, qq2 = ln2 >> 4;
        int k = c * 32 + qq2 * 8 + e;
        float v = 0.f;
        int grow = (t == 0) ? ((cc2 < 8) ? (g0 + cc2) : (Hsz + g0 + cc2 - 8))
                            : ((cc2 < 8) ? (2 * Hsz + g0 + cc2) : -1);
        if (grow >= 0) {
            if (k < Hsz) v = W_hh[(size_t)grow * Hsz + k];
            else if (k - Hsz < Vsz) v = W_ih[grow * Vsz + (k - Hsz)];
        }
        unsigned short t1 = btrunc(v); float r1 = v - bup(t1);
        unsigned short t2 = btrunc(r1); float r2 = r1 - bup(t2);
        unsigned short t3 = btrunc(r2);
        Bst[idx] = (p == 0) ? t1 : (p == 1) ? t2 : t3;
    }
    if (j < 2) {
        for (int idx = tid; idx < 16 * 512; idx += NT) {
            int e = idx & 7; int ln2 = (idx >> 3) & 63; int c = idx >> 9;
            int cc2 = ln2 & 15, qq2 = ln2 >> 4;
            int k = c * 32 + qq2 * 8 + e;
            int vr = (j == 0) ? cc2 : 16 + cc2;
            Dst[idx] = (vr < Vsz) ? brne(W_dec[(size_t)vr * Hsz + k]) : (unsigned short)0;
        }
    }
    if (tid < NG) {
        int grow = (tid < 8) ? g0 + tid : (tid < 16 ? Hsz + g0 + tid - 8 : 2 * Hsz + g0 + tid - 16);
        bihL[tid] = b_ih[grow]; bhhL[tid] = b_hh[grow];
    }

    const int w   = tid >> 6;          // wave id = M-tile
    const int ln  = tid & 63;
    const int cc  = ln & 15;
    const int qq  = ln >> 4;
    const int rowA = (w << 4) + cc;
    const int xr = tid >> 2, xc = (tid & 3) << 3;
    const int vcol = (j == 0) ? cc : 16 + cc;     // decode column (j<2)
    const float bdv = (j < 2 && vcol < Vsz) ? b_dec[vcol] : 0.f;
    unsigned* mycnt = cnt + bt;
    const __amdgpu_buffer_rsrc_t hrs = make_rsrc((void*)hpl, 2u * 3u * BH * 2u);

    // x_0 staging
    {
        #pragma unroll
        for (int e = 0; e < 8; ++e) {
            int ci = xc + e;
            xs[xr][ci] = (ci < Vsz) ? x[(size_t)(b0 + xr) * TV + ci] : 0.f;
        }
    }
    float hk[4] = {0.f, 0.f, 0.f, 0.f};   // own h' slice carried in regs (h_0=0)
    __syncthreads();

    for (int i = 0; i <= Tsz; ++i) {
        // prefetch x_{i+1} to regs (plain loads; x is read-only -> L2 fine)
        float xreg[8];
        if (i + 1 < Tsz) {
            #pragma unroll
            for (int e = 0; e < 8; ++e) {
                int ci = xc + e;
                xreg[e] = (ci < Vsz) ? x[(size_t)(b0 + xr) * TV + (size_t)(i + 1) * Vsz + ci] : 0.f;
            }
        }

        const int par = (i & 1) * (3 * BH * 2);
        const int voffA0 = par + (((b0 + rowA) * Hsz + (qq << 3)) << 1);

        f32x4 accRZ = {0.f,0.f,0.f,0.f}, accNh = {0.f,0.f,0.f,0.f};
        f32x4 accNi = {0.f,0.f,0.f,0.f}, accD  = {0.f,0.f,0.f,0.f};

        // 1-deep A-register prefetch pipeline over the 16 K-chunks
        s16x8 A1c = bload128_c(hrs, voffA0);
        s16x8 A2c = bload128_c(hrs, voffA0 + BH * 2);
        s16x8 A3c = bload128_c(hrs, voffA0 + 2 * BH * 2);
        #pragma unroll
        for (int c = 0; c < 16; ++c) {
            s16x8 A1n, A2n, A3n;
            if (c < 15) {
                A1n = bload128_c(hrs, voffA0 + (c + 1) * 64);
                A2n = bload128_c(hrs, voffA0 + (c + 1) * 64 + BH * 2);
                A3n = bload128_c(hrs, voffA0 + (c + 1) * 64 + 2 * BH * 2);
            }
            const unsigned short* bs = Bst + c * (6 * 512) + (ln << 3);
            {   // tile0: r,z gates
                s16x8 B1 = *(const s16x8*)(bs);
                s16x8 B2 = *(const s16x8*)(bs + 512);
                s16x8 B3 = *(const s16x8*)(bs + 1024);
                accRZ = MFMA(A1c, B1, accRZ, 0, 0, 0);
                accRZ = MFMA(A1c, B2, accRZ, 0, 0, 0);
                accRZ = MFMA(A2c, B1, accRZ, 0, 0, 0);
                accRZ = MFMA(A1c, B3, accRZ, 0, 0, 0);
                accRZ = MFMA(A2c, B2, accRZ, 0, 0, 0);
                accRZ = MFMA(A3c, B1, accRZ, 0, 0, 0);
            }
            {   // tile1: n-gate h-part
                s16x8 C1 = *(const s16x8*)(bs + 1536);
                s16x8 C2 = *(const s16x8*)(bs + 2048);
                s16x8 C3 = *(const s16x8*)(bs + 2560);
                accNh = MFMA(A1c, C1, accNh, 0, 0, 0);
                accNh = MFMA(A1c, C2, accNh, 0, 0, 0);
                accNh = MFMA(A2c, C1, accNh, 0, 0, 0);
                accNh = MFMA(A1c, C3, accNh, 0, 0, 0);
                accNh = MFMA(A2c, C2, accNh, 0, 0, 0);
                accNh = MFMA(A3c, C1, accNh, 0, 0, 0);
            }
            if (j < 2) {   // fused decode of h_i (this block's v-rows only)
                s16x8 D1 = *(const s16x8*)(Dst + (c << 9) + (ln << 3));
                accD = MFMA(A1c, D1, accD, 0, 0, 0);
                accD = MFMA(A2c, D1, accD, 0, 0, 0);
            }
            A1c = A1n; A2c = A2n; A3c = A3n;
        }

        // K-chunk 16: fold x-projection (triple-split fp32 x from LDS)
        if (i < Tsz) {
            f32x4 fa = *(const f32x4*)&xs[rowA][qq << 3];
            f32x4 fb = *(const f32x4*)&xs[rowA][(qq << 3) + 4];
            s16x8 A1, A2, A3;
            #pragma unroll
            for (int e = 0; e < 8; ++e) {
                float v = (e < 4) ? fa[e & 3] : fb[e & 3];
                unsigned short s1 = btrunc(v); float r1 = v - bup(s1);
                unsigned short s2 = btrunc(r1); float r2 = r1 - bup(s2);
                unsigned short s3 = btrunc(r2);
                A1[e] = (short)s1; A2[e] = (short)s2; A3[e] = (short)s3;
            }
            const unsigned short* bs = Bst + 16 * (6 * 512) + (ln << 3);
            {   // r,z x-part
                s16x8 B1 = *(const s16x8*)(bs);
                s16x8 B2 = *(const s16x8*)(bs + 512);
                s16x8 B3 = *(const s16x8*)(bs + 1024);
                accRZ = MFMA(A1, B1, accRZ, 0, 0, 0);
                accRZ = MFMA(A1, B2, accRZ, 0, 0, 0);
                accRZ = MFMA(A2, B1, accRZ, 0, 0, 0);
                accRZ = MFMA(A1, B3, accRZ, 0, 0, 0);
                accRZ = MFMA(A2, B2, accRZ, 0, 0, 0);
                accRZ = MFMA(A3, B1, accRZ, 0, 0, 0);
            }
            {   // n-gate x-part (separate accumulator per GRU semantics)
                s16x8 C1 = *(const s16x8*)(bs + 1536);
                s16x8 C2 = *(const s16x8*)(bs + 2048);
                s16x8 C3 = *(const s16x8*)(bs + 2560);
                accNi = MFMA(A1, C1, accNi, 0, 0, 0);
                accNi = MFMA(A1, C2, accNi, 0, 0, 0);
                accNi = MFMA(A2, C1, accNi, 0, 0, 0);
                accNi = MFMA(A1, C3, accNi, 0, 0, 0);
                accNi = MFMA(A2, C2, accNi, 0, 0, 0);
                accNi = MFMA(A3, C1, accNi, 0, 0, 0);
            }
        }

        __syncthreads();                 // all x-folds done -> xs reusable
        if (i + 1 < Tsz) {
            #pragma unroll
            for (int e = 0; e < 8; ++e) xs[xr][xc + e] = xreg[e];
        }

        // z-gate lives on lane cc+8 of same qq-quad
        float zsh[4];
        #pragma unroll
        for (int r = 0; r < 4; ++r)
            zsh[r] = __shfl(accRZ[r], (ln & 48) | (cc + 8));

        if (i < Tsz && cc < 8) {
            const int wpar = ((i + 1) & 1) * (3 * BH * 2);
            #pragma unroll
            for (int r = 0; r < 4; ++r) {
                float rv = accRZ[r] + bihL[cc] + bhhL[cc];
                float zv = zsh[r] + bihL[8 + cc] + bhhL[8 + cc];
                float nh = accNh[r] + bhhL[16 + cc];
                float ni = accNi[r] + bihL[16 + cc];
                float rg = 1.f / (1.f + expf(-rv));
                float zg = 1.f / (1.f + expf(-zv));
                float ng = tanhf(ni + rg * nh);
                float hv = (1.f - zg) * ng + zg * hk[r];
                hk[r] = hv;   // own slice for next step, in regs
                int e2 = ((b0 + (w << 4) + (qq << 2) + r) * Hsz + g0 + cc) << 1;
                unsigned short s1 = btrunc(hv); float r1 = hv - bup(s1);
                unsigned short s2 = btrunc(r1); float r2 = r1 - bup(s2);
                unsigned short s3 = btrunc(r2);
                __builtin_amdgcn_raw_buffer_store_b16(s1, hrs, wpar + e2, 0, CPOL_WT);
                __builtin_amdgcn_raw_buffer_store_b16(s2, hrs, wpar + e2 + BH * 2, 0, CPOL_WT);
                __builtin_amdgcn_raw_buffer_store_b16(s3, hrs, wpar + e2 + 2 * BH * 2, 0, CPOL_WT);
            }
        }
        if (i < Tsz) {
            // h write-through stores must reach the coherence point first
            asm volatile("s_waitcnt vmcnt(0)" ::: "memory");
            group_barrier(mycnt, 64u * (unsigned)(i + 1));
        }
        // logits[:, i-1, :] from h_i — after barrier, overlaps next K-loop
        if (i > 0 && j < 2 && vcol < Vsz) {
            #pragma unroll
            for (int r = 0; r < 4; ++r) {
                size_t brow = (size_t)(b0 + (w << 4) + (qq << 2) + r);
                out[brow * TV + (size_t)(i - 1) * Vsz + vcol] = accD[r] + bdv;
            }
        }
    }
}

extern "C" void kernel_launch(void* const* d_in, const int* in_sizes, int n_in,
                              void* d_out, int out_size, void* d_ws, size_t ws_size,
                              hipStream_t stream) {
    const float* x     = (const float*)d_in[0];
    const float* W_ih  = (const float*)d_in[1];
    const float* W_hh  = (const float*)d_in[2];
    const float* b_ih  = (const float*)d_in[3];
    const float* b_hh  = (const float*)d_in[4];
    const float* W_dec = (const float*)d_in[5];
    const float* b_dec = (const float*)d_in[6];
    float* out  = (float*)d_out;
    unsigned short* hpl = (unsigned short*)d_ws;   // 2 bufs x 3 planes x 512KB = 3 MB
    unsigned* cnt = (unsigned*)((char*)d_ws + (size_t)2 * 3 * BH * sizeof(unsigned short));

    init_ws_kernel<<<768, 256, 0, stream>>>(hpl, cnt);

    // Plain launch: ~136 KB LDS -> 1 block/CU, grid == 256 == CU count ->
    // all blocks co-resident; group barriers cannot deadlock (R4-R10-proven).
    gru_persist<<<dim3(NBLK), dim3(NT), 0, stream>>>(
        x, W_ih, W_hh, b_ih, b_hh, W_dec, b_dec, hpl, cnt, out);
}

// Round 12
// 16790.836 us; speedup vs baseline: 1.2272x; 1.2272x over previous
//
#include <hip/hip_runtime.h>
#include <math.h>

#define Bsz 512
#define Tsz 1024
#define Vsz 27
#define Hsz 512
#define BH (Bsz * Hsz)
#define TV (Tsz * Vsz)
#define NBLK 256
#define NT 512
#define BT 64        // batch rows per group: 8 groups x 32 j-blocks
#define JB 32        // blocks per group
#define NG 48        // gate rows per block (16 r + 16 z + 16 n), HPc=16

typedef float f32x4 __attribute__((ext_vector_type(4)));
typedef short s16x8 __attribute__((ext_vector_type(8)));
typedef unsigned int u32x4 __attribute__((ext_vector_type(4)));
#define MFMA __builtin_amdgcn_mfma_f32_16x16x32_bf16

// ws byte offsets
#define WS_CNT  ((size_t)2 * 3 * BH * 2)            // after 3MB h planes
#define WS_PCNT (WS_CNT + 64)
#define WS_FLAG (WS_CNT + 128)
#define WS_DSTG (WS_CNT + 2048)                     // 32KB decode stream
#define WS_WXG  (WS_DSTG + (size_t)2 * 16 * 512 * 2) // 192KB x-fold W stream

__device__ __forceinline__ unsigned short btrunc(float x) {   // bf16 RTZ bits
    return (unsigned short)(__float_as_uint(x) >> 16);
}
__device__ __forceinline__ float bup(unsigned short b) {
    return __uint_as_float(((unsigned)b) << 16);
}
__device__ __forceinline__ unsigned short brne(float x) {     // bf16 RNE bits
    unsigned u = __float_as_uint(x);
    return (unsigned short)((u + 0x7FFFu + ((u >> 16) & 1u)) >> 16);
}
__device__ __forceinline__ __amdgpu_buffer_rsrc_t make_rsrc(void* p, unsigned bytes) {
    return __builtin_amdgcn_make_buffer_rsrc(p, (short)0, (int)bytes, 0x00020000);
}
template<bool FAST>
__device__ __forceinline__ s16x8 loadA(__amdgpu_buffer_rsrc_t r, int off) {
    u32x4 d = __builtin_amdgcn_raw_buffer_load_b128(r, off, 0, FAST ? 0 : 0x11);
    return __builtin_bit_cast(s16x8, d);
}
template<bool FAST>
__device__ __forceinline__ void storeH(__amdgpu_buffer_rsrc_t r, int off, unsigned short v) {
    __builtin_amdgcn_raw_buffer_store_b16(v, r, off, 0, FAST ? 0 : 0x11);
}

// 6-product triple-split fp32-grade MFMA (R7-R10 proven)
#define PROD6(ACC, B1_, B2_, B3_, A1_, A2_, A3_) do { \
    ACC = MFMA(A1_, B1_, ACC, 0, 0, 0); \
    ACC = MFMA(A1_, B2_, ACC, 0, 0, 0); \
    ACC = MFMA(A2_, B1_, ACC, 0, 0, 0); \
    ACC = MFMA(A1_, B3_, ACC, 0, 0, 0); \
    ACC = MFMA(A2_, B2_, ACC, 0, 0, 0); \
    ACC = MFMA(A3_, B1_, ACC, 0, 0, 0); } while (0)
#define PROD5(ACC, B1_, B2_, A1_, A2_, A3_) do { \
    ACC = MFMA(A1_, B1_, ACC, 0, 0, 0); \
    ACC = MFMA(A1_, B2_, ACC, 0, 0, 0); \
    ACC = MFMA(A2_, B1_, ACC, 0, 0, 0); \
    ACC = MFMA(A2_, B2_, ACC, 0, 0, 0); \
    ACC = MFMA(A3_, B1_, ACC, 0, 0, 0); } while (0)

__global__ void init_ws_kernel(unsigned short* __restrict__ hpl, unsigned* __restrict__ cnt,
                               unsigned* __restrict__ pcnt, unsigned* __restrict__ flag,
                               unsigned short* __restrict__ Dstg, unsigned short* __restrict__ Wxg,
                               const float* __restrict__ W_ih, const float* __restrict__ W_dec)
{
    size_t gid = (size_t)blockIdx.x * 256 + threadIdx.x;
    size_t gsz = (size_t)gridDim.x * 256;
    for (size_t i = gid; i < (size_t)(2 * 3 * BH * 2) / 16; i += gsz)
        ((uint4*)hpl)[i] = make_uint4(0u, 0u, 0u, 0u);
    if (gid < 16) { cnt[gid] = 0u; pcnt[gid] = 0u; flag[gid] = 0u; }
    // decode stream [jj:2][c:16][lane:64][8]
    for (size_t i = gid; i < 2 * 16 * 512; i += gsz) {
        int e = i & 7, ln2 = (i >> 3) & 63, c = (i >> 9) & 15, jj = (int)(i >> 13);
        int cc2 = ln2 & 15, qq2 = ln2 >> 4;
        int k = c * 32 + qq2 * 8 + e;
        int vr = jj * 16 + cc2;
        Dstg[i] = (vr < Vsz) ? brne(W_dec[(size_t)vr * Hsz + k]) : (unsigned short)0;
    }
    // x-fold W stream [grow:1536][p:2][k:32] (2-plane RTZ split of W_ih, k>=27 pad)
    for (size_t i = gid; i < 1536 * 64; i += gsz) {
        int k = i & 31, p = (i >> 5) & 1, grow = (int)(i >> 6);
        float v = (k < Vsz) ? W_ih[grow * Vsz + k] : 0.f;
        unsigned short t1 = btrunc(v); float r1 = v - bup(t1);
        unsigned short t2 = btrunc(r1);
        Wxg[i] = p ? t2 : t1;
    }
}

// relaxed add + relaxed poll, NO fences (R10-proven shell)
__device__ __forceinline__ void group_barrier(unsigned* c, unsigned target) {
    __syncthreads();
    if (threadIdx.x == 0) {
        __hip_atomic_fetch_add(c, 1u, __ATOMIC_RELAXED, __HIP_MEMORY_SCOPE_AGENT);
        while (__hip_atomic_load(c, __ATOMIC_RELAXED, __HIP_MEMORY_SCOPE_AGENT) < target)
            __builtin_amdgcn_s_sleep(2);
    }
    __syncthreads();
}

template<bool FAST>
__device__ __forceinline__ void gru_loop(
    const float* __restrict__ x, float* __restrict__ out,
    const unsigned short* __restrict__ Dstg, const unsigned short* __restrict__ Wxg,
    unsigned* __restrict__ cnt, __amdgpu_buffer_rsrc_t hrs,
    const unsigned short* Bst, float* xs, float* nscr,
    const float* bihL, const float* bhhL, float bdv,
    int tid, int bt, int j, int b0, int g0)
{
    const int w = tid >> 6, ln = tid & 63;
    const int m = w & 3, half = w >> 2;
    const int cc = ln & 15, qq = ln >> 4;
    const int rowA = (m << 4) + cc;
    const int xr = tid >> 3, xc = (tid & 7) << 2;
    const int vcol = (j << 4) + cc;
    unsigned* mycnt = cnt + bt;
    const int rowBase = ((b0 + rowA) * Hsz + (qq << 3)) << 1;   // bytes

    float hk[4] = {0.f, 0.f, 0.f, 0.f};

    for (int i = 0; i <= Tsz; ++i) {
        if (FAST) {   // invalidate this CU's L1 (stale lines from step i-2)
            asm volatile("buffer_inv" ::: "memory");
            asm volatile("s_waitcnt vmcnt(0)" ::: "memory");
        }
        // prefetch x_{i+1} to regs
        float xreg[4];
        if (i + 1 < Tsz) {
            #pragma unroll
            for (int e = 0; e < 4; ++e) {
                int ci = xc + e;
                xreg[e] = (ci < Vsz) ? x[(size_t)(b0 + xr) * TV + (size_t)(i + 1) * Vsz + ci] : 0.f;
            }
        }
        const int voffA0 = (i & 1) * (3 * BH * 2) + rowBase;

        f32x4 accR = {0,0,0,0}, accZ = {0,0,0,0}, accNi = {0,0,0,0};
        f32x4 accNh = {0,0,0,0}, accD = {0,0,0,0};

        // 4-deep A register pipeline
        s16x8 A1s[4], A2s[4], A3s[4];
        #pragma unroll
        for (int c0 = 0; c0 < 4; ++c0) {
            A1s[c0] = loadA<FAST>(hrs, voffA0 + c0 * 64);
            A2s[c0] = loadA<FAST>(hrs, voffA0 + c0 * 64 + BH * 2);
            A3s[c0] = loadA<FAST>(hrs, voffA0 + c0 * 64 + 2 * BH * 2);
        }
        #pragma unroll
        for (int c = 0; c < 16; ++c) {
            const int sl = c & 3;
            s16x8 A1 = A1s[sl], A2 = A2s[sl], A3 = A3s[sl];
            const unsigned short* bs = Bst + (size_t)(c * 9) * 512 + (ln << 3);
            if (half == 0) {
                s16x8 B1 = *(const s16x8*)(bs);
                s16x8 B2 = *(const s16x8*)(bs + 512);
                s16x8 B3 = *(const s16x8*)(bs + 1024);
                PROD6(accR, B1, B2, B3, A1, A2, A3);
                s16x8 C1 = *(const s16x8*)(bs + 1536);
                s16x8 C2 = *(const s16x8*)(bs + 2048);
                s16x8 C3 = *(const s16x8*)(bs + 2560);
                PROD6(accZ, C1, C2, C3, A1, A2, A3);
            } else {
                s16x8 N1 = *(const s16x8*)(bs + 3072);
                s16x8 N2 = *(const s16x8*)(bs + 3584);
                s16x8 N3 = *(const s16x8*)(bs + 4096);
                PROD6(accNh, N1, N2, N3, A1, A2, A3);
                if (j < 2) {
                    s16x8 D1 = *(const s16x8*)(Dstg + (size_t)((j << 4) + c) * 512 + (ln << 3));
                    accD = MFMA(A1, D1, accD, 0, 0, 0);
                    accD = MFMA(A2, D1, accD, 0, 0, 0);
                }
            }
            if (c < 12) {
                const int cn = c + 4;
                A1s[sl] = loadA<FAST>(hrs, voffA0 + cn * 64);
                A2s[sl] = loadA<FAST>(hrs, voffA0 + cn * 64 + BH * 2);
                A3s[sl] = loadA<FAST>(hrs, voffA0 + cn * 64 + 2 * BH * 2);
            }
        }

        // x-fold (half0): triple-split x from LDS, 2-plane W from global stream
        if (half == 0 && i < Tsz) {
            s16x8 A1, A2, A3;
            #pragma unroll
            for (int e = 0; e < 8; ++e) {
                float v = xs[rowA * 32 + (qq << 3) + e];
                unsigned short s1 = btrunc(v); float r1 = v - bup(s1);
                unsigned short s2 = btrunc(r1); float r2 = r1 - bup(s2);
                unsigned short s3 = btrunc(r2);
                A1[e] = (short)s1; A2[e] = (short)s2; A3[e] = (short)s3;
            }
            {
                const unsigned short* wb = Wxg + (size_t)(g0 + cc) * 64 + (qq << 3);
                s16x8 B1 = *(const s16x8*)(wb);
                s16x8 B2 = *(const s16x8*)(wb + 32);
                PROD5(accR, B1, B2, A1, A2, A3);
            }
            {
                const unsigned short* wb = Wxg + (size_t)(Hsz + g0 + cc) * 64 + (qq << 3);
                s16x8 B1 = *(const s16x8*)(wb);
                s16x8 B2 = *(const s16x8*)(wb + 32);
                PROD5(accZ, B1, B2, A1, A2, A3);
            }
            {
                const unsigned short* wb = Wxg + (size_t)(2 * Hsz + g0 + cc) * 64 + (qq << 3);
                s16x8 B1 = *(const s16x8*)(wb);
                s16x8 B2 = *(const s16x8*)(wb + 32);
                PROD5(accNi, B1, B2, A1, A2, A3);
            }
        }

        __syncthreads();   // S2: xs reads done, half1 MFMAs done
        if (half == 1 && i < Tsz)
            *(f32x4*)&nscr[(size_t)(m * 64 + ln) * 4] = accNh;
        if (i + 1 < Tsz) {
            #pragma unroll
            for (int e = 0; e < 4; ++e) xs[xr * 32 + xc + e] = xreg[e];
        }
        __syncthreads();   // S3: nscr ready

        if (half == 0 && i < Tsz) {
            const int wpar = ((i + 1) & 1) * (3 * BH * 2);
            const float* nh4 = &nscr[(size_t)(m * 64 + ln) * 4];
            #pragma unroll
            for (int r = 0; r < 4; ++r) {
                float rv = accR[r] + bihL[cc] + bhhL[cc];
                float zv = accZ[r] + bihL[16 + cc] + bhhL[16 + cc];
                float ni = accNi[r] + bihL[32 + cc];
                float nh = nh4[r] + bhhL[32 + cc];
                float rg = 1.f / (1.f + expf(-rv));
                float zg = 1.f / (1.f + expf(-zv));
                float ng = tanhf(ni + rg * nh);
                float hv = (1.f - zg) * ng + zg * hk[r];
                hk[r] = hv;
                int e2 = wpar + (((b0 + (m << 4) + (qq << 2) + r) * Hsz + g0 + cc) << 1);
                unsigned short s1 = btrunc(hv); float r1 = hv - bup(s1);
                unsigned short s2 = btrunc(r1); float r2 = r1 - bup(s2);
                unsigned short s3 = btrunc(r2);
                storeH<FAST>(hrs, e2, s1);
                storeH<FAST>(hrs, e2 + BH * 2, s2);
                storeH<FAST>(hrs, e2 + 2 * BH * 2, s3);
            }
        }
        if (i < Tsz) {
            asm volatile("s_waitcnt vmcnt(0)" ::: "memory");   // h stores visible
            group_barrier(mycnt, (unsigned)JB * (unsigned)(i + 1));
        }
        // logits[:, i-1, :] from h_i (after barrier; overlaps next step)
        if (i > 0 && half == 1 && j < 2 && vcol < Vsz) {
            #pragma unroll
            for (int r = 0; r < 4; ++r) {
                size_t brow = (size_t)(b0 + (m << 4) + (qq << 2) + r);
                out[brow * TV + (size_t)(i - 1) * Vsz + vcol] = accD[r] + bdv;
            }
        }
    }
}

__global__ __launch_bounds__(NT, 2) void gru_persist(
    const float* __restrict__ x, const float* __restrict__ W_ih,
    const float* __restrict__ W_hh, const float* __restrict__ b_ih,
    const float* __restrict__ b_hh, const float* __restrict__ W_dec,
    const float* __restrict__ b_dec, char* __restrict__ wsb,
    float* __restrict__ out)
{
    __shared__ unsigned short Bst[16 * 9 * 512];   // [c][tile*plane][lane][8] 144KB
    __shared__ float xs[BT * 32];                  // 8KB
    __shared__ float nscr[4 * 64 * 4];             // 4KB n-gate exchange
    __shared__ float bihL[NG], bhhL[NG];
    __shared__ int fastFlag;

    unsigned short* hpl = (unsigned short*)wsb;
    unsigned* cnt  = (unsigned*)(wsb + WS_CNT);
    unsigned* pcnt = (unsigned*)(wsb + WS_PCNT);
    unsigned* flag = (unsigned*)(wsb + WS_FLAG);
    unsigned short* Dstg = (unsigned short*)(wsb + WS_DSTG);
    unsigned short* Wxg  = (unsigned short*)(wsb + WS_WXG);

    const int tid = threadIdx.x;
    const int bt  = blockIdx.x & 7;     // group == XCD if round-robin holds
    const int j   = blockIdx.x >> 3;    // 0..31
    const int b0  = bt * BT;
    const int g0  = j * 16;

    // ---- one-time: B-stream (triple-split W_hh, fragment-linear) ----
    for (int idx = tid; idx < 16 * 9 * 512; idx += NT) {
        int e = idx & 7, ln2 = (idx >> 3) & 63, s = idx >> 9;
        int p = s % 3, t = (s / 3) % 3, c = s / 9;
        int cc2 = ln2 & 15, qq2 = ln2 >> 4;
        int k = c * 32 + qq2 * 8 + e;
        int grow = t * Hsz + g0 + cc2;
        float v = W_hh[(size_t)grow * Hsz + k];
        unsigned short t1 = btrunc(v); float r1 = v - bup(t1);
        unsigned short t2 = btrunc(r1); float r2 = r1 - bup(t2);
        unsigned short t3 = btrunc(r2);
        Bst[idx] = (p == 0) ? t1 : (p == 1) ? t2 : t3;
    }
    if (tid < NG) {
        int grow = (tid >> 4) * Hsz + g0 + (tid & 15);
        bihL[tid] = b_ih[grow]; bhhL[tid] = b_hh[grow];
    }
    // x_0 staging
    {
        int xr = tid >> 3, xc = (tid & 7) << 2;
        #pragma unroll
        for (int e = 0; e < 4; ++e) {
            int ci = xc + e;
            xs[xr * 32 + ci] = (ci < Vsz) ? x[(size_t)(b0 + xr) * TV + ci] : 0.f;
        }
    }
    // ---- XCD consensus: fast path iff whole group on one XCD ----
    if (tid == 0) {
        unsigned xcc;
        asm volatile("s_getreg_b32 %0, hwreg(20, 0, 32)" : "=s"(xcc));
        __hip_atomic_fetch_or(flag + bt, 1u << (xcc & 31), __ATOMIC_RELAXED,
                              __HIP_MEMORY_SCOPE_AGENT);
        asm volatile("s_waitcnt vmcnt(0)" ::: "memory");
    }
    group_barrier(pcnt + bt, JB);
    if (tid == 0) {
        unsigned f = __hip_atomic_load(flag + bt, __ATOMIC_RELAXED, __HIP_MEMORY_SCOPE_AGENT);
        fastFlag = (__popc(f) == 1) ? 1 : 0;
    }
    __syncthreads();
    const bool fastv = (fastFlag != 0);

    const int cc = tid & 15;
    const int vcol = (j << 4) + cc;
    const float bdv = (j < 2 && vcol < Vsz) ? b_dec[vcol] : 0.f;
    __amdgpu_buffer_rsrc_t hrs = make_rsrc((void*)hpl, (unsigned)(2u * 3u * BH * 2u));

    if (fastv)
        gru_loop<true>(x, out, Dstg, Wxg, cnt, hrs, Bst, xs, nscr, bihL, bhhL, bdv,
                       tid, bt, j, b0, g0);
    else
        gru_loop<false>(x, out, Dstg, Wxg, cnt, hrs, Bst, xs, nscr, bihL, bhhL, bdv,
                        tid, bt, j, b0, g0);
}

extern "C" void kernel_launch(void* const* d_in, const int* in_sizes, int n_in,
                              void* d_out, int out_size, void* d_ws, size_t ws_size,
                              hipStream_t stream) {
    const float* x     = (const float*)d_in[0];
    const float* W_ih  = (const float*)d_in[1];
    const float* W_hh  = (const float*)d_in[2];
    const float* b_ih  = (const float*)d_in[3];
    const float* b_hh  = (const float*)d_in[4];
    const float* W_dec = (const float*)d_in[5];
    const float* b_dec = (const float*)d_in[6];
    float* out = (float*)d_out;
    char* wsb  = (char*)d_ws;

    init_ws_kernel<<<768, 256, 0, stream>>>(
        (unsigned short*)wsb, (unsigned*)(wsb + WS_CNT), (unsigned*)(wsb + WS_PCNT),
        (unsigned*)(wsb + WS_FLAG), (unsigned short*)(wsb + WS_DSTG),
        (unsigned short*)(wsb + WS_WXG), W_ih, W_dec);

    // Plain launch: ~157 KB LDS -> 1 block/CU, grid == 256 == CU count ->
    // all blocks co-resident; group barriers cannot deadlock (R4-R11-proven).
    gru_persist<<<dim3(NBLK), dim3(NT), 0, stream>>>(
        x, W_ih, W_hh, b_ih, b_hh, W_dec, b_dec, wsb, out);
}